// Round 6
// baseline (481.661 us; speedup 1.0000x reference)
//
#include <hip/hip_runtime.h>
#include <hip/hip_cooperative_groups.h>
#include <cstdint>
#include <cstddef>

namespace cg = cooperative_groups;

#define DIM    256
#define BATCH  4096
#define STEPS  12

typedef _Float16 f16x8 __attribute__((ext_vector_type(8)));
typedef _Float16 f16x4 __attribute__((ext_vector_type(4)));
typedef float    f32x4 __attribute__((ext_vector_type(4)));

// ---- ws float-slot offsets (regions overlap across phases) ----
#define OFF_APK  0u        // 4096x512 halfs (pack..gemm) -> S after
#define OFF_S    0u        // 4096x256 f32
#define OFF_BPK  1048576u  // 4096x512 halfs (pack..gemm) -> U after
#define OFF_U    1048576u  // 64x64x256 f32
#define OFF_GX   2097152u
#define OFF_XN   2101248u
#define OFF_CN   2105344u
#define OFF_MD   2109440u
#define OFF_WCNT 2113536u
#define OFF_PV   2117632u
#define OFF_PI   2248704u
#define OFF_CNT  2379776u  // ..2383872 slots = 9.54 MB

// ---- out float offsets ----
#define OUT_BMU  1048576u
#define OUT_MD   1056768u

__device__ __forceinline__ void load_lds16(const void* g, void* l) {
  __builtin_amdgcn_global_load_lds(
      (const __attribute__((address_space(1))) unsigned int*)g,
      (__attribute__((address_space(3))) unsigned int*)l, 16, 0, 0);
}

// ======================= fused cooperative mega-kernel =======================
__global__ __launch_bounds__(256, 2) void som_mega(
    const float* __restrict__ x, const float* __restrict__ cen,
    const float* __restrict__ lr, float* __restrict__ ws,
    float* __restrict__ out) {
  cg::grid_group grid = cg::this_grid();
  __shared__ __align__(16) unsigned char smem[65536];

  const int bid  = blockIdx.x;
  const int tid  = threadIdx.x;
  const int lane = tid & 63;
  const int w    = tid >> 6;

  _Float16* Apk = (_Float16*)(ws + OFF_APK);
  _Float16* Bpk = (_Float16*)(ws + OFF_BPK);
  float* S    = ws + OFF_S;
  float* U    = ws + OFF_U;
  float* Gx   = ws + OFF_GX;
  float* xn   = ws + OFF_XN;
  float* cnw  = ws + OFF_CN;
  float* md   = ws + OFF_MD;
  float* Wcnt = ws + OFF_WCNT;
  float* pv   = ws + OFF_PV;
  int*   pi   = (int*)(ws + OFF_PI);
  float* cnt  = ws + OFF_CNT;

  // ===== P0: pack f16 hi/lo + norms + Gx (blk0) + zero cnt (blk1) =====
  {
#pragma unroll
    for (int pass = 0; pass < 4; ++pass) {
      int row = bid * 16 + pass * 4 + w;
      bool isx = row < BATCH;
      const float* src = isx ? (x + (size_t)row * DIM)
                             : (cen + (size_t)(row - BATCH) * DIM);
      float4 v = *(const float4*)(src + lane * 4);
      _Float16 h0 = (_Float16)v.x, h1 = (_Float16)v.y,
               h2 = (_Float16)v.z, h3 = (_Float16)v.w;
      _Float16 l0 = (_Float16)(v.x - (float)h0), l1 = (_Float16)(v.y - (float)h1),
               l2 = (_Float16)(v.z - (float)h2), l3 = (_Float16)(v.w - (float)h3);
      _Float16* dst = (isx ? Apk : Bpk) + (size_t)(isx ? row : row - BATCH) * 512;
      *(f16x4*)(dst + lane * 4)       = (f16x4){h0, h1, h2, h3};
      *(f16x4*)(dst + 256 + lane * 4) = (f16x4){l0, l1, l2, l3};
      float s = v.x * v.x + v.y * v.y + v.z * v.z + v.w * v.w;
#pragma unroll
      for (int off = 32; off >= 1; off >>= 1) s += __shfl_xor(s, off);
      if (lane == 0) { if (isx) xn[row] = s; else cnw[row - BATCH] = s; }
    }
    if (bid == 0) {
      float sg  = 32.f * lr[0];
      float inv = 1.f / (2.f * sg * sg + 1e-5f);
#pragma unroll
      for (int i = 0; i < 16; ++i) {
        int g = i * 256 + tid;
        float d = (float)((g >> 6) - (g & 63));
        Gx[g] = expf(-d * d * inv);
      }
    } else if (bid == 1) {
      float4 z = {0.f, 0.f, 0.f, 0.f};
#pragma unroll
      for (int i = 0; i < 4; ++i) ((float4*)cnt)[i * 256 + tid] = z;
    }
  }
  grid.sync();

  // ===== P1: MFMA f16-split GEMM (2 tiles/block) + argmin partials =====
  {
    auto lds = (_Float16(*)[2][8192])smem;
    const int wr = w >> 1, wc = w & 1;
    const int by = bid >> 4, bxp = bid & 15;
    const int row0 = by * 128;
    const int t15 = lane & 15, q = lane >> 4;
    const int swz = t15 & 7;
    const int srow = w * 32 + (lane >> 3);
    const int schunk = (lane & 7) ^ ((lane >> 3) & 7);

    for (int tt = 0; tt < 2; ++tt) {
      const int bx = bxp * 2 + tt;
      const int col0 = bx * 128;
      f32x4 acc[4][4];
#pragma unroll
      for (int m = 0; m < 4; ++m)
#pragma unroll
        for (int n = 0; n < 4; ++n) acc[m][n] = (f32x4){0.f, 0.f, 0.f, 0.f};

      auto STAGE = [&](int b, int step) {
        const int seg = step >> 2, k = (step & 3) << 6;
        const int aoff = ((seg == 2) ? 256 : 0) + k;
        const int boff = ((seg == 1) ? 256 : 0) + k;
        const _Float16* Ab = Apk + (size_t)(row0 + srow) * 512 + aoff + schunk * 8;
        const _Float16* Bb = Bpk + (size_t)(col0 + srow) * 512 + boff + schunk * 8;
        _Float16* Al = &lds[b][0][w * 2048];
        _Float16* Bl = &lds[b][1][w * 2048];
#pragma unroll
        for (int i = 0; i < 4; ++i) {
          load_lds16(Ab + (size_t)i * 8 * 512, Al + i * 512);
          load_lds16(Bb + (size_t)i * 8 * 512, Bl + i * 512);
        }
      };

      STAGE(0, 0);
      for (int t = 0; t < STEPS; ++t) {
        const int b = t & 1;
        __syncthreads();                    // drains vmcnt: tile t staged
        if (t + 1 < STEPS) STAGE(b ^ 1, t + 1);
#pragma unroll
        for (int kk = 0; kk < 2; ++kk) {
          f16x8 af[4], bf[4];
#pragma unroll
          for (int m = 0; m < 4; ++m) {
            int r = wr * 64 + m * 16 + t15;
            af[m] = *(const f16x8*)&lds[b][0][r * 64 + (((kk * 4 + q) ^ swz) * 8)];
          }
#pragma unroll
          for (int n = 0; n < 4; ++n) {
            int r = wc * 64 + n * 16 + t15;
            bf[n] = *(const f16x8*)&lds[b][1][r * 64 + (((kk * 4 + q) ^ swz) * 8)];
          }
#pragma unroll
          for (int m = 0; m < 4; ++m)
#pragma unroll
            for (int n = 0; n < 4; ++n)
              acc[m][n] = __builtin_amdgcn_mfma_f32_16x16x32_f16(af[m], bf[n], acc[m][n], 0, 0, 0);
        }
      }
      __syncthreads();

      float cnv[4];
#pragma unroll
      for (int n = 0; n < 4; ++n) cnv[n] = cnw[col0 + wc * 64 + n * 16 + t15];

      float* cv = (float*)smem;
      int*   ci = (int*)(smem + 16384);
#pragma unroll
      for (int m = 0; m < 4; ++m) {
#pragma unroll
        for (int reg = 0; reg < 4; ++reg) {
          float bv = 1e30f; int bi = 0x7fffffff;
#pragma unroll
          for (int n = 0; n < 4; ++n) {
            float v = cnv[n] - 2.f * acc[m][n][reg];
            if (v < bv) { bv = v; bi = col0 + wc * 64 + n * 16 + t15; }
          }
#pragma unroll
          for (int off = 1; off < 16; off <<= 1) {
            float ov = __shfl_xor(bv, off);
            int   oi = __shfl_xor(bi, off);
            if (ov < bv || (ov == bv && oi < bi)) { bv = ov; bi = oi; }
          }
          if (t15 == 0) {
            int r = wr * 64 + m * 16 + q * 4 + reg;
            cv[r * 2 + wc] = bv;
            ci[r * 2 + wc] = bi;
          }
        }
      }
      __syncthreads();
      if (tid < 128) {
        float v0 = cv[tid * 2];     int i0 = ci[tid * 2];
        float v1 = cv[tid * 2 + 1]; int i1 = ci[tid * 2 + 1];
        if (v1 < v0 || (v1 == v0 && i1 < i0)) { v0 = v1; i0 = i1; }
        pv[(size_t)(row0 + tid) * 32 + bx] = v0;
        pi[(size_t)(row0 + tid) * 32 + bx] = i0;
      }
      __syncthreads();
    }
  }
  grid.sync();

  // ===== P1.5: zero S (overlaps dead Apk) =====
  {
    float4 z = {0.f, 0.f, 0.f, 0.f};
    float4* S4 = (float4*)S;
    S4[bid * 512 + tid] = z;
    S4[bid * 512 + 256 + tid] = z;
  }
  grid.sync();

  // ===== P2: finalize — BMU, bmu_loc, md, scatter S/cnt =====
  {
#pragma unroll
    for (int i = 0; i < 2; ++i) {
      int b = bid * 8 + w * 2 + i;
      float v = pv[(size_t)b * 32 + (lane & 31)];
      int idx  = pi[(size_t)b * 32 + (lane & 31)];
#pragma unroll
      for (int off = 16; off >= 1; off >>= 1) {
        float ov = __shfl_xor(v, off);
        int   oi = __shfl_xor(idx, off);
        if (ov < v || (ov == v && oi < idx)) { v = ov; idx = oi; }
      }
      if (lane == 0) {
        md[b] = sqrtf(fmaxf(xn[b] + v, 0.f));
        out[OUT_BMU + (size_t)b * 2 + 0] = (float)(idx >> 6);
        out[OUT_BMU + (size_t)b * 2 + 1] = (float)(idx & 63);
        atomicAdd(cnt + idx, 1.f);
      }
#pragma unroll
      for (int c = 0; c < 4; ++c)
        atomicAdd(S + (size_t)idx * DIM + c * 64 + lane,
                  x[(size_t)b * DIM + c * 64 + lane]);
    }
  }
  grid.sync();

  // ===== P3: e1 (blk 0-255) || wcnt (blk 256-271) || md-red (blk 272) =====
  if (bid < 256) {
    float* Ss = (float*)smem;
    const int dd = lane, gq = w;
    const int kj = bid >> 2, dq = bid & 3;
    for (int i = 0; i < 16; ++i) {
      int ki = i * 4 + gq;
      Ss[ki * 64 + dd] = S[((size_t)ki * 64 + kj) * 256 + dq * 64 + dd];
    }
    __syncthreads();
    float a[16];
#pragma unroll
    for (int gg = 0; gg < 16; ++gg) a[gg] = 0.f;
    for (int ki = 0; ki < 64; ++ki) {
      float s = Ss[ki * 64 + dd];
#pragma unroll
      for (int gg = 0; gg < 16; ++gg)
        a[gg] += Gx[ki * 64 + gq * 16 + gg] * s;
    }
#pragma unroll
    for (int gg = 0; gg < 16; ++gg)
      U[((size_t)(gq * 16 + gg) * 64 + kj) * 256 + dq * 64 + dd] = a[gg];
  } else if (bid < 272) {
    float* cs = (float*)smem;
    float* gs = cs + 4096;
    float* inner = gs + 4096;
    const int t = tid;
    for (int i = 0; i < 16; i++) { cs[i * 256 + t] = cnt[i * 256 + t]; gs[i * 256 + t] = Gx[i * 256 + t]; }
    __syncthreads();
    for (int i = 0; i < 16; i++) {
      int idx = i * 256 + t; int ki = idx >> 6, gj = idx & 63;
      float a = 0.f;
      for (int kj2 = 0; kj2 < 64; kj2++) a += gs[kj2 * 64 + gj] * cs[ki * 64 + kj2];
      inner[idx] = a;
    }
    __syncthreads();
    const int g = (bid - 256) * 256 + t, gi = g >> 6, gj = g & 63;
    float a = 0.f;
    for (int ki = 0; ki < 64; ki++) a += gs[gi * 64 + ki] * inner[ki * 64 + gj];
    Wcnt[g] = a;
  } else if (bid == 272) {
    float s = 0.f;
#pragma unroll
    for (int i = 0; i < 16; i++) s += md[i * 256 + tid];
#pragma unroll
    for (int off = 32; off >= 1; off >>= 1) s += __shfl_xor(s, off);
    float* wsum = (float*)smem;
    if (lane == 0) wsum[w] = s;
    __syncthreads();
    if (tid == 0) out[OUT_MD] = (wsum[0] + wsum[1] + wsum[2] + wsum[3]) * (1.f / (float)BATCH);
  }
  grid.sync();

  // ===== P4: e2 + fused centroid write (blk 0-255) =====
  if (bid < 256) {
    float* Us = (float*)smem;
    const int dd = lane, gq = w;
    const int gi = bid >> 2, dq = bid & 3;
    for (int i = 0; i < 16; ++i) {
      int kj = i * 4 + gq;
      Us[kj * 64 + dd] = U[((size_t)gi * 64 + kj) * 256 + dq * 64 + dd];
    }
    __syncthreads();
    float a[16];
#pragma unroll
    for (int gg = 0; gg < 16; ++gg) a[gg] = 0.f;
    for (int kj = 0; kj < 64; ++kj) {
      float s = Us[kj * 64 + dd];
#pragma unroll
      for (int gg = 0; gg < 16; ++gg)
        a[gg] += Gx[kj * 64 + gq * 16 + gg] * s;
    }
    const float coef = 0.5f * lr[0] / (float)BATCH;
#pragma unroll
    for (int gg = 0; gg < 16; ++gg) {
      int g = gi * 64 + gq * 16 + gg;
      float c = cen[(size_t)g * 256 + dq * 64 + dd];
      out[(size_t)g * 256 + dq * 64 + dd] = c + coef * (a[gg] - Wcnt[g] * c);
    }
  }
}

// ======================= fallback multi-kernel chain (proven R3) =============
__global__ __launch_bounds__(256) void packnorm_kernel(
    const float* __restrict__ x, const float* __restrict__ cen,
    const float* __restrict__ lr,
    _Float16* __restrict__ Apk, _Float16* __restrict__ Bpk,
    float* __restrict__ xn, float* __restrict__ cn, float* __restrict__ Gx) {
  int row  = blockIdx.x * 4 + (threadIdx.x >> 6);
  int lane = threadIdx.x & 63;
  bool isx = row < BATCH;
  const float* src = isx ? (x + (size_t)row * DIM)
                         : (cen + (size_t)(row - BATCH) * DIM);
  float4 v = *(const float4*)(src + lane * 4);
  _Float16 h0 = (_Float16)v.x, h1 = (_Float16)v.y,
           h2 = (_Float16)v.z, h3 = (_Float16)v.w;
  _Float16 l0 = (_Float16)(v.x - (float)h0), l1 = (_Float16)(v.y - (float)h1),
           l2 = (_Float16)(v.z - (float)h2), l3 = (_Float16)(v.w - (float)h3);
  _Float16* dst = (isx ? Apk : Bpk) + (size_t)(isx ? row : row - BATCH) * 512;
  *(f16x4*)(dst + lane * 4)       = (f16x4){h0, h1, h2, h3};
  *(f16x4*)(dst + 256 + lane * 4) = (f16x4){l0, l1, l2, l3};
  float s = v.x * v.x + v.y * v.y + v.z * v.z + v.w * v.w;
#pragma unroll
  for (int off = 32; off >= 1; off >>= 1) s += __shfl_xor(s, off);
  if (lane == 0) { if (isx) xn[row] = s; else cn[row - BATCH] = s; }
  if (blockIdx.x == 0) {
    float sg  = 32.f * lr[0];
    float inv = 1.f / (2.f * sg * sg + 1e-5f);
#pragma unroll
    for (int i = 0; i < 16; ++i) {
      int g = i * 256 + threadIdx.x;
      float d = (float)((g >> 6) - (g & 63));
      Gx[g] = expf(-d * d * inv);
    }
  }
}

__global__ __launch_bounds__(256) void gemm_argmin_kernel(
    const _Float16* __restrict__ Apk, const _Float16* __restrict__ Bpk,
    const float* __restrict__ cnorm, float* __restrict__ pv, int* __restrict__ pi) {
  __shared__ __align__(16) _Float16 lds[2][2][8192];
  const int tid  = threadIdx.x;
  const int lane = tid & 63, w = tid >> 6;
  const int wr = w >> 1, wc = w & 1;
  const int row0 = blockIdx.y * 128, col0 = blockIdx.x * 128;
  const int t15 = lane & 15, q = lane >> 4;
  const int sw  = t15 & 7;
  const int srow   = w * 32 + (lane >> 3);
  const int schunk = (lane & 7) ^ ((lane >> 3) & 7);

  f32x4 acc[4][4];
#pragma unroll
  for (int m = 0; m < 4; ++m)
#pragma unroll
    for (int n = 0; n < 4; ++n) acc[m][n] = (f32x4){0.f, 0.f, 0.f, 0.f};

  auto STAGE = [&](int b, int step) {
    const int seg = step >> 2, k = (step & 3) << 6;
    const int aoff = ((seg == 2) ? 256 : 0) + k;
    const int boff = ((seg == 1) ? 256 : 0) + k;
    const _Float16* Ab = Apk + (size_t)(row0 + srow) * 512 + aoff + schunk * 8;
    const _Float16* Bb = Bpk + (size_t)(col0 + srow) * 512 + boff + schunk * 8;
    _Float16* Al = &lds[b][0][w * 2048];
    _Float16* Bl = &lds[b][1][w * 2048];
#pragma unroll
    for (int i = 0; i < 4; ++i) {
      load_lds16(Ab + (size_t)i * 8 * 512, Al + i * 512);
      load_lds16(Bb + (size_t)i * 8 * 512, Bl + i * 512);
    }
  };

  STAGE(0, 0);
  for (int t = 0; t < STEPS; ++t) {
    const int b = t & 1;
    __syncthreads();
    if (t + 1 < STEPS) STAGE(b ^ 1, t + 1);
#pragma unroll
    for (int kk = 0; kk < 2; ++kk) {
      f16x8 af[4], bf[4];
#pragma unroll
      for (int m = 0; m < 4; ++m) {
        int r = wr * 64 + m * 16 + t15;
        af[m] = *(const f16x8*)&lds[b][0][r * 64 + (((kk * 4 + q) ^ sw) * 8)];
      }
#pragma unroll
      for (int n = 0; n < 4; ++n) {
        int r = wc * 64 + n * 16 + t15;
        bf[n] = *(const f16x8*)&lds[b][1][r * 64 + (((kk * 4 + q) ^ sw) * 8)];
      }
#pragma unroll
      for (int m = 0; m < 4; ++m)
#pragma unroll
        for (int n = 0; n < 4; ++n)
          acc[m][n] = __builtin_amdgcn_mfma_f32_16x16x32_f16(af[m], bf[n], acc[m][n], 0, 0, 0);
    }
  }
  __syncthreads();

  float cnv[4];
#pragma unroll
  for (int n = 0; n < 4; ++n) cnv[n] = cnorm[col0 + wc * 64 + n * 16 + t15];

  float* cv = (float*)&lds[0][0][0];
  int*   ci = (int*)&lds[0][1][0];
#pragma unroll
  for (int m = 0; m < 4; ++m) {
#pragma unroll
    for (int reg = 0; reg < 4; ++reg) {
      float bv = 1e30f; int bi = 0x7fffffff;
#pragma unroll
      for (int n = 0; n < 4; ++n) {
        float v = cnv[n] - 2.f * acc[m][n][reg];
        if (v < bv) { bv = v; bi = col0 + wc * 64 + n * 16 + t15; }
      }
#pragma unroll
      for (int off = 1; off < 16; off <<= 1) {
        float ov = __shfl_xor(bv, off);
        int   oi = __shfl_xor(bi, off);
        if (ov < bv || (ov == bv && oi < bi)) { bv = ov; bi = oi; }
      }
      if (t15 == 0) {
        int r = wr * 64 + m * 16 + q * 4 + reg;
        cv[r * 2 + wc] = bv;
        ci[r * 2 + wc] = bi;
      }
    }
  }
  __syncthreads();
  if (tid < 128) {
    float v0 = cv[tid * 2];     int i0 = ci[tid * 2];
    float v1 = cv[tid * 2 + 1]; int i1 = ci[tid * 2 + 1];
    if (v1 < v0 || (v1 == v0 && i1 < i0)) { v0 = v1; i0 = i1; }
    pv[(size_t)(row0 + tid) * 32 + blockIdx.x] = v0;
    pi[(size_t)(row0 + tid) * 32 + blockIdx.x] = i0;
  }
}

__global__ __launch_bounds__(256) void finalize_kernel(
    const float* __restrict__ pv, const int* __restrict__ pi,
    const float* __restrict__ xn, const float* __restrict__ x,
    float* __restrict__ S, float* __restrict__ cnt,
    float* __restrict__ md, float* __restrict__ out) {
  const int w = threadIdx.x >> 6, l = threadIdx.x & 63;
  const int b = blockIdx.x * 4 + w;
  float v = pv[(size_t)b * 32 + (l & 31)];
  int idx  = pi[(size_t)b * 32 + (l & 31)];
#pragma unroll
  for (int off = 16; off >= 1; off >>= 1) {
    float ov = __shfl_xor(v, off);
    int   oi = __shfl_xor(idx, off);
    if (ov < v || (ov == v && oi < idx)) { v = ov; idx = oi; }
  }
  if (l == 0) {
    md[b] = sqrtf(fmaxf(xn[b] + v, 0.f));
    out[OUT_BMU + (size_t)b * 2 + 0] = (float)(idx >> 6);
    out[OUT_BMU + (size_t)b * 2 + 1] = (float)(idx & 63);
    atomicAdd(cnt + idx, 1.f);
  }
#pragma unroll
  for (int c = 0; c < 4; ++c)
    atomicAdd(S + (size_t)idx * DIM + c * 64 + l, x[(size_t)b * DIM + c * 64 + l]);
}

__global__ __launch_bounds__(256) void wcnt_kernel(const float* __restrict__ cnt,
                                                   const float* __restrict__ Gx,
                                                   const float* __restrict__ md,
                                                   float* __restrict__ Wcnt,
                                                   float* __restrict__ out) {
  __shared__ float cs[4096], gs[4096], inner[4096];
  const int t = threadIdx.x;
  for (int i = 0; i < 16; i++) { cs[i * 256 + t] = cnt[i * 256 + t]; gs[i * 256 + t] = Gx[i * 256 + t]; }
  __syncthreads();
  for (int i = 0; i < 16; i++) {
    int idx = i * 256 + t; int ki = idx >> 6, gj = idx & 63;
    float a = 0.f;
    for (int kj = 0; kj < 64; kj++) a += gs[kj * 64 + gj] * cs[ki * 64 + kj];
    inner[idx] = a;
  }
  __syncthreads();
  const int g = blockIdx.x * 256 + t, gi = g >> 6, gj = g & 63;
  float a = 0.f;
  for (int ki = 0; ki < 64; ki++) a += gs[gi * 64 + ki] * inner[ki * 64 + gj];
  Wcnt[g] = a;
  if (blockIdx.x == 0) {
    float s = 0.f;
#pragma unroll
    for (int i = 0; i < 16; i++) s += md[i * 256 + t];
#pragma unroll
    for (int off = 32; off >= 1; off >>= 1) s += __shfl_xor(s, off);
    __shared__ float wsum[4];
    if ((t & 63) == 0) wsum[t >> 6] = s;
    __syncthreads();
    if (t == 0) out[OUT_MD] = (wsum[0] + wsum[1] + wsum[2] + wsum[3]) * (1.f / (float)BATCH);
  }
}

__global__ __launch_bounds__(256) void e1_kernel(const float* __restrict__ S,
                                                 const float* __restrict__ Gx,
                                                 float* __restrict__ U) {
  __shared__ float Ss[4096];
  const int t = threadIdx.x, dd = t & 63, gq = t >> 6;
  const int kj = blockIdx.x >> 2, dq = blockIdx.x & 3;
#pragma unroll 4
  for (int i = 0; i < 16; ++i) {
    int ki = i * 4 + gq;
    Ss[ki * 64 + dd] = S[((size_t)ki * 64 + kj) * 256 + dq * 64 + dd];
  }
  __syncthreads();
  float a[16];
#pragma unroll
  for (int gg = 0; gg < 16; ++gg) a[gg] = 0.f;
  for (int ki = 0; ki < 64; ++ki) {
    float s = Ss[ki * 64 + dd];
#pragma unroll
    for (int gg = 0; gg < 16; ++gg)
      a[gg] += Gx[ki * 64 + gq * 16 + gg] * s;
  }
#pragma unroll
  for (int gg = 0; gg < 16; ++gg)
    U[((size_t)(gq * 16 + gg) * 64 + kj) * 256 + dq * 64 + dd] = a[gg];
}

__global__ __launch_bounds__(256) void e2_kernel(const float* __restrict__ U,
                                                 const float* __restrict__ Gx,
                                                 const float* __restrict__ Wcnt,
                                                 const float* __restrict__ cen,
                                                 const float* __restrict__ lr,
                                                 float* __restrict__ out) {
  __shared__ float Us[4096];
  const int t = threadIdx.x, dd = t & 63, gq = t >> 6;
  const int gi = blockIdx.x >> 2, dq = blockIdx.x & 3;
#pragma unroll 4
  for (int i = 0; i < 16; ++i) {
    int kj = i * 4 + gq;
    Us[kj * 64 + dd] = U[((size_t)gi * 64 + kj) * 256 + dq * 64 + dd];
  }
  __syncthreads();
  float a[16];
#pragma unroll
  for (int gg = 0; gg < 16; ++gg) a[gg] = 0.f;
  for (int kj = 0; kj < 64; ++kj) {
    float s = Us[kj * 64 + dd];
#pragma unroll
    for (int gg = 0; gg < 16; ++gg)
      a[gg] += Gx[kj * 64 + gq * 16 + gg] * s;
  }
  const float coef = 0.5f * lr[0] / (float)BATCH;
#pragma unroll
  for (int gg = 0; gg < 16; ++gg) {
    int g = gi * 64 + gq * 16 + gg;
    float c = cen[(size_t)g * 256 + dq * 64 + dd];
    out[(size_t)g * 256 + dq * 64 + dd] = c + coef * (a[gg] - Wcnt[g] * c);
  }
}

extern "C" void kernel_launch(void* const* d_in, const int* in_sizes, int n_in,
                              void* d_out, int out_size, void* d_ws, size_t ws_size,
                              hipStream_t stream) {
  const float* x   = (const float*)d_in[0];
  const float* cen = (const float*)d_in[1];
  const float* lr  = (const float*)d_in[4];
  float* out = (float*)d_out;
  float* ws  = (float*)d_ws;

  _Float16* Apk = (_Float16*)(ws + OFF_APK);
  _Float16* Bpk = (_Float16*)(ws + OFF_BPK);
  float* S    = ws + OFF_S;
  float* U    = ws + OFF_U;
  float* Gx   = ws + OFF_GX;
  float* xn   = ws + OFF_XN;
  float* cnw  = ws + OFF_CN;
  float* md   = ws + OFF_MD;
  float* Wcnt = ws + OFF_WCNT;
  float* pv   = ws + OFF_PV;
  int*   pi   = (int*)(ws + OFF_PI);
  float* cnt  = ws + OFF_CNT;

  void* args[] = { (void*)&x, (void*)&cen, (void*)&lr, (void*)&ws, (void*)&out };
  hipError_t err = hipLaunchCooperativeKernel((const void*)som_mega, dim3(512),
                                              dim3(256), args, 0, stream);
  if (err != hipSuccess) {
    // fallback: proven multi-kernel chain (same math, same ws layout)
    packnorm_kernel<<<2048, 256, 0, stream>>>(x, cen, lr, Apk, Bpk, xn, cnw, Gx);
    gemm_argmin_kernel<<<dim3(32, 32), 256, 0, stream>>>(Apk, Bpk, cnw, pv, pi);
    hipMemsetAsync(S, 0, (size_t)1048576 * sizeof(float), stream);
    hipMemsetAsync(cnt, 0, (size_t)4096 * sizeof(float), stream);
    finalize_kernel<<<1024, 256, 0, stream>>>(pv, pi, xn, x, S, cnt, md, out);
    wcnt_kernel<<<16, 256, 0, stream>>>(cnt, Gx, md, Wcnt, out);
    e1_kernel<<<256, 256, 0, stream>>>(S, Gx, U);
    e2_kernel<<<256, 256, 0, stream>>>(U, Gx, Wcnt, cen, lr, out);
  }
}

// Round 7
// 181.116 us; speedup vs baseline: 2.6594x; 2.6594x over previous
//
#include <hip/hip_runtime.h>
#include <cstdint>
#include <cstddef>

#define DIM    256
#define BATCH  4096
#define STEPS  12

typedef _Float16 f16x8 __attribute__((ext_vector_type(8)));
typedef _Float16 f16x4 __attribute__((ext_vector_type(4)));
typedef float    f32x4 __attribute__((ext_vector_type(4)));

// ---- ws float-slot offsets (regions overlap across pipeline phases) ----
#define OFF_APK  0u        // 4096x512 halfs [hi|lo] (pack..gemm)
#define OFF_S    0u        // 4096x256 f32 (memset after gemm)
#define OFF_BPK  1048576u  // 4096x512 halfs (pack..gemm)
#define OFF_CNT  1048576u  // 4096 f32 (contiguous with S -> one memset)
#define OFF_U    1052672u  // 64x64x256 f32 (e1..e2)
#define OFF_GX   2101248u
#define OFF_WCNT 2105344u
#define OFF_XN   2109440u
#define OFF_CN   2113536u
#define OFF_MD   2117632u
#define OFF_PV   2121728u
#define OFF_PI   2252800u  // ..2383872 slots = 9.54 MB

// ---- out float offsets ----
#define OUT_BMU  1048576u
#define OUT_MD   1056768u

__device__ __forceinline__ void load_lds16(const void* g, void* l) {
  __builtin_amdgcn_global_load_lds(
      (const __attribute__((address_space(1))) unsigned int*)g,
      (__attribute__((address_space(3))) unsigned int*)l, 16, 0, 0);
}

// ---------------- pack f16 hi/lo + norms + Gx (block 0) ----------------
__global__ __launch_bounds__(256) void packnorm_kernel(
    const float* __restrict__ x, const float* __restrict__ cen,
    const float* __restrict__ lr,
    _Float16* __restrict__ Apk, _Float16* __restrict__ Bpk,
    float* __restrict__ xn, float* __restrict__ cn, float* __restrict__ Gx) {
  int row  = blockIdx.x * 4 + (threadIdx.x >> 6);
  int lane = threadIdx.x & 63;
  bool isx = row < BATCH;
  const float* src = isx ? (x + (size_t)row * DIM)
                         : (cen + (size_t)(row - BATCH) * DIM);
  float4 v = *(const float4*)(src + lane * 4);
  _Float16 h0 = (_Float16)v.x, h1 = (_Float16)v.y,
           h2 = (_Float16)v.z, h3 = (_Float16)v.w;
  _Float16 l0 = (_Float16)(v.x - (float)h0), l1 = (_Float16)(v.y - (float)h1),
           l2 = (_Float16)(v.z - (float)h2), l3 = (_Float16)(v.w - (float)h3);
  _Float16* dst = (isx ? Apk : Bpk) + (size_t)(isx ? row : row - BATCH) * 512;
  *(f16x4*)(dst + lane * 4)       = (f16x4){h0, h1, h2, h3};
  *(f16x4*)(dst + 256 + lane * 4) = (f16x4){l0, l1, l2, l3};
  float s = v.x * v.x + v.y * v.y + v.z * v.z + v.w * v.w;
#pragma unroll
  for (int off = 32; off >= 1; off >>= 1) s += __shfl_xor(s, off);
  if (lane == 0) { if (isx) xn[row] = s; else cn[row - BATCH] = s; }
  if (blockIdx.x == 0) {
    float sg  = 32.f * lr[0];
    float inv = 1.f / (2.f * sg * sg + 1e-5f);
#pragma unroll
    for (int i = 0; i < 16; ++i) {
      int g = i * 256 + threadIdx.x;
      float d = (float)((g >> 6) - (g & 63));
      Gx[g] = expf(-d * d * inv);
    }
  }
}

// ---- MFMA f16-split GEMM, BK=64, SINGLE buffer (32KB LDS -> 5 blocks/CU),
// ---- m97-style 2-barriers-per-step, conflict-free XOR-swizzled LDS ----
__global__ __launch_bounds__(256) void gemm_argmin_kernel(
    const _Float16* __restrict__ Apk, const _Float16* __restrict__ Bpk,
    const float* __restrict__ cnorm, float* __restrict__ pv, int* __restrict__ pi) {
  __shared__ __align__(16) _Float16 lds[2][8192];   // [A/B][128r x 64k] = 32 KiB
  const int tid  = threadIdx.x;
  const int lane = tid & 63, w = tid >> 6;
  const int wr = w >> 1, wc = w & 1;
  const int row0 = blockIdx.y * 128, col0 = blockIdx.x * 128;
  const int t15 = lane & 15, q = lane >> 4;
  const int sw  = t15 & 7;                       // read-side row-swizzle key
  const int srow   = w * 32 + (lane >> 3);       // staging row (+ i*8)
  const int schunk = (lane & 7) ^ ((lane >> 3) & 7);  // pre-swizzled source chunk

  f32x4 acc[4][4];
#pragma unroll
  for (int m = 0; m < 4; ++m)
#pragma unroll
    for (int n = 0; n < 4; ++n) acc[m][n] = (f32x4){0.f, 0.f, 0.f, 0.f};

  for (int t = 0; t < STEPS; ++t) {
    if (t) __syncthreads();            // prior step's ds_reads done
    {
      const int seg = t >> 2, k = (t & 3) << 6;
      const int aoff = ((seg == 2) ? 256 : 0) + k;   // term 2 uses A-lo
      const int boff = ((seg == 1) ? 256 : 0) + k;   // term 1 uses B-lo
      const _Float16* Ab = Apk + (size_t)(row0 + srow) * 512 + aoff + schunk * 8;
      const _Float16* Bb = Bpk + (size_t)(col0 + srow) * 512 + boff + schunk * 8;
      _Float16* Al = &lds[0][w * 2048];
      _Float16* Bl = &lds[1][w * 2048];
#pragma unroll
      for (int i = 0; i < 4; ++i) {
        load_lds16(Ab + (size_t)i * 8 * 512, Al + i * 512);
        load_lds16(Bb + (size_t)i * 8 * 512, Bl + i * 512);
      }
    }
    __syncthreads();                   // drains vmcnt: tile staged
#pragma unroll
    for (int kk = 0; kk < 2; ++kk) {
      f16x8 af[4], bf[4];
#pragma unroll
      for (int m = 0; m < 4; ++m) {
        int r = wr * 64 + m * 16 + t15;
        af[m] = *(const f16x8*)&lds[0][r * 64 + (((kk * 4 + q) ^ sw) * 8)];
      }
#pragma unroll
      for (int n = 0; n < 4; ++n) {
        int r = wc * 64 + n * 16 + t15;
        bf[n] = *(const f16x8*)&lds[1][r * 64 + (((kk * 4 + q) ^ sw) * 8)];
      }
#pragma unroll
      for (int m = 0; m < 4; ++m)
#pragma unroll
        for (int n = 0; n < 4; ++n)
          acc[m][n] = __builtin_amdgcn_mfma_f32_16x16x32_f16(af[m], bf[n], acc[m][n], 0, 0, 0);
    }
  }
  __syncthreads();                     // all ds_reads done before LDS reuse

  // epilogue: v = cnorm[c] - 2*dot; per-row first-min over this 128-col block
  float cnv[4];
#pragma unroll
  for (int n = 0; n < 4; ++n) cnv[n] = cnorm[col0 + wc * 64 + n * 16 + t15];

  float* cv = (float*)&lds[0][0];      // [128][2]
  int*   ci = (int*)&lds[1][0];        // [128][2]
#pragma unroll
  for (int m = 0; m < 4; ++m) {
#pragma unroll
    for (int reg = 0; reg < 4; ++reg) {
      float bv = 1e30f; int bi = 0x7fffffff;
#pragma unroll
      for (int n = 0; n < 4; ++n) {    // cols ascend with n -> first-min
        float v = cnv[n] - 2.f * acc[m][n][reg];
        if (v < bv) { bv = v; bi = col0 + wc * 64 + n * 16 + t15; }
      }
#pragma unroll
      for (int off = 1; off < 16; off <<= 1) {
        float ov = __shfl_xor(bv, off);
        int   oi = __shfl_xor(bi, off);
        if (ov < bv || (ov == bv && oi < bi)) { bv = ov; bi = oi; }
      }
      if (t15 == 0) {
        int r = wr * 64 + m * 16 + q * 4 + reg;
        cv[r * 2 + wc] = bv;
        ci[r * 2 + wc] = bi;
      }
    }
  }
  __syncthreads();
  if (tid < 128) {
    float v0 = cv[tid * 2];     int i0 = ci[tid * 2];
    float v1 = cv[tid * 2 + 1]; int i1 = ci[tid * 2 + 1];
    if (v1 < v0 || (v1 == v0 && i1 < i0)) { v0 = v1; i0 = i1; }
    pv[(size_t)(row0 + tid) * 32 + blockIdx.x] = v0;
    pi[(size_t)(row0 + tid) * 32 + blockIdx.x] = i0;
  }
}

// ------- finalize: 4 rows/block, wavewide reduce, no LDS, scatter S/cnt -------
__global__ __launch_bounds__(256) void finalize_kernel(
    const float* __restrict__ pv, const int* __restrict__ pi,
    const float* __restrict__ xn, const float* __restrict__ x,
    float* __restrict__ S, float* __restrict__ cnt,
    float* __restrict__ md, float* __restrict__ out) {
  const int w = threadIdx.x >> 6, l = threadIdx.x & 63;
  const int b = blockIdx.x * 4 + w;
  float v = pv[(size_t)b * 32 + (l & 31)];     // both 32-halves load same data
  int idx  = pi[(size_t)b * 32 + (l & 31)];
#pragma unroll
  for (int off = 16; off >= 1; off >>= 1) {
    float ov = __shfl_xor(v, off);
    int   oi = __shfl_xor(idx, off);
    if (ov < v || (ov == v && oi < idx)) { v = ov; idx = oi; }
  }
  if (l == 0) {
    md[b] = sqrtf(fmaxf(xn[b] + v, 0.f));
    out[OUT_BMU + (size_t)b * 2 + 0] = (float)(idx >> 6);
    out[OUT_BMU + (size_t)b * 2 + 1] = (float)(idx & 63);
    atomicAdd(cnt + idx, 1.f);
  }
#pragma unroll
  for (int c = 0; c < 4; ++c)
    atomicAdd(S + (size_t)idx * DIM + c * 64 + l, x[(size_t)b * DIM + c * 64 + l]);
}

// --- e1 (blk 0-255) || wcnt (blk 256-271) || md-reduce (blk 272) ---
__global__ __launch_bounds__(256) void e1_kernel(const float* __restrict__ S,
                                                 const float* __restrict__ Gx,
                                                 const float* __restrict__ cnt,
                                                 const float* __restrict__ md,
                                                 float* __restrict__ U,
                                                 float* __restrict__ Wcnt,
                                                 float* __restrict__ out) {
  __shared__ float smem[12288];        // 48 KiB shared across branches
  const int bid = blockIdx.x, tid = threadIdx.x;
  if (bid < 256) {
    float* Ss = smem;                  // [64 ki][64 dd]
    const int dd = tid & 63, gq = tid >> 6;
    const int kj = bid >> 2, dq = bid & 3;
#pragma unroll 4
    for (int i = 0; i < 16; ++i) {
      int ki = i * 4 + gq;
      Ss[ki * 64 + dd] = S[((size_t)ki * 64 + kj) * 256 + dq * 64 + dd];
    }
    __syncthreads();
    float a[16];
#pragma unroll
    for (int gg = 0; gg < 16; ++gg) a[gg] = 0.f;
    for (int ki = 0; ki < 64; ++ki) {
      float s = Ss[ki * 64 + dd];
#pragma unroll
      for (int gg = 0; gg < 16; ++gg)
        a[gg] += Gx[ki * 64 + gq * 16 + gg] * s;   // wave-uniform -> s_load
    }
#pragma unroll
    for (int gg = 0; gg < 16; ++gg)
      U[((size_t)(gq * 16 + gg) * 64 + kj) * 256 + dq * 64 + dd] = a[gg];
  } else if (bid < 272) {
    float* cs = smem;
    float* gs = smem + 4096;
    float* inner = smem + 8192;
    for (int i = 0; i < 16; i++) { cs[i * 256 + tid] = cnt[i * 256 + tid]; gs[i * 256 + tid] = Gx[i * 256 + tid]; }
    __syncthreads();
    for (int i = 0; i < 16; i++) {
      int idx = i * 256 + tid; int ki = idx >> 6, gj = idx & 63;
      float a = 0.f;
      for (int kj = 0; kj < 64; kj++) a += gs[kj * 64 + gj] * cs[ki * 64 + kj];
      inner[idx] = a;
    }
    __syncthreads();
    const int g = (bid - 256) * 256 + tid, gi = g >> 6, gj = g & 63;
    float a = 0.f;
    for (int ki = 0; ki < 64; ki++) a += gs[gi * 64 + ki] * inner[ki * 64 + gj];
    Wcnt[g] = a;
  } else {
    float s = 0.f;
#pragma unroll
    for (int i = 0; i < 16; i++) s += md[i * 256 + tid];
#pragma unroll
    for (int off = 32; off >= 1; off >>= 1) s += __shfl_xor(s, off);
    if ((tid & 63) == 0) smem[tid >> 6] = s;
    __syncthreads();
    if (tid == 0) out[OUT_MD] = (smem[0] + smem[1] + smem[2] + smem[3]) * (1.f / (float)BATCH);
  }
}

// --- e2 + fused centroid write ; grid (gi,dquad)=256 ---
__global__ __launch_bounds__(256) void e2_kernel(const float* __restrict__ U,
                                                 const float* __restrict__ Gx,
                                                 const float* __restrict__ Wcnt,
                                                 const float* __restrict__ cen,
                                                 const float* __restrict__ lr,
                                                 float* __restrict__ out) {
  __shared__ float Us[4096];           // [64 kj][64 dd]
  const int t = threadIdx.x, dd = t & 63, gq = t >> 6;
  const int gi = blockIdx.x >> 2, dq = blockIdx.x & 3;
#pragma unroll 4
  for (int i = 0; i < 16; ++i) {
    int kj = i * 4 + gq;
    Us[kj * 64 + dd] = U[((size_t)gi * 64 + kj) * 256 + dq * 64 + dd];
  }
  __syncthreads();
  float a[16];
#pragma unroll
  for (int gg = 0; gg < 16; ++gg) a[gg] = 0.f;
  for (int kj = 0; kj < 64; ++kj) {
    float s = Us[kj * 64 + dd];
#pragma unroll
    for (int gg = 0; gg < 16; ++gg)
      a[gg] += Gx[kj * 64 + gq * 16 + gg] * s;
  }
  const float coef = 0.5f * lr[0] / (float)BATCH;
#pragma unroll
  for (int gg = 0; gg < 16; ++gg) {
    int g = gi * 64 + gq * 16 + gg;
    float c = cen[(size_t)g * 256 + dq * 64 + dd];
    out[(size_t)g * 256 + dq * 64 + dd] = c + coef * (a[gg] - Wcnt[g] * c);
  }
}

extern "C" void kernel_launch(void* const* d_in, const int* in_sizes, int n_in,
                              void* d_out, int out_size, void* d_ws, size_t ws_size,
                              hipStream_t stream) {
  const float* x   = (const float*)d_in[0];
  const float* cen = (const float*)d_in[1];
  const float* lr  = (const float*)d_in[4];
  float* out = (float*)d_out;
  float* ws  = (float*)d_ws;

  _Float16* Apk = (_Float16*)(ws + OFF_APK);
  _Float16* Bpk = (_Float16*)(ws + OFF_BPK);
  float* S    = ws + OFF_S;
  float* cnt  = ws + OFF_CNT;
  float* U    = ws + OFF_U;
  float* Gx   = ws + OFF_GX;
  float* Wcnt = ws + OFF_WCNT;
  float* xn   = ws + OFF_XN;
  float* cnw  = ws + OFF_CN;
  float* md   = ws + OFF_MD;
  float* pv   = ws + OFF_PV;
  int*   pi   = (int*)(ws + OFF_PI);

  packnorm_kernel<<<2048, 256, 0, stream>>>(x, cen, lr, Apk, Bpk, xn, cnw, Gx);
  gemm_argmin_kernel<<<dim3(32, 32), 256, 0, stream>>>(Apk, Bpk, cnw, pv, pi);
  hipMemsetAsync(S, 0, (size_t)(1048576 + 4096) * sizeof(float), stream);  // S+cnt
  finalize_kernel<<<1024, 256, 0, stream>>>(pv, pi, xn, x, S, cnt, md, out);
  e1_kernel<<<273, 256, 0, stream>>>(S, Gx, cnt, md, U, Wcnt, out);
  e2_kernel<<<256, 256, 0, stream>>>(U, Gx, Wcnt, cen, lr, out);
}

// Round 8
// 180.741 us; speedup vs baseline: 2.6649x; 1.0021x over previous
//
#include <hip/hip_runtime.h>
#include <cstdint>
#include <cstddef>

#define DIM    256
#define BATCH  4096
#define KSTEPS 8            // K=256, BK=32

typedef _Float16 f16x8 __attribute__((ext_vector_type(8)));
typedef _Float16 f16x4 __attribute__((ext_vector_type(4)));
typedef float    f32x4 __attribute__((ext_vector_type(4)));

// ---- ws float-slot offsets (regions overlap across pipeline phases) ----
#define OFF_APK  0u        // 4096x512 halfs [hi|lo] (pack..gemm)
#define OFF_S    0u        // 4096x256 f32 (memset after gemm)
#define OFF_BPK  1048576u  // 4096x512 halfs (pack..gemm)
#define OFF_CNT  1048576u  // 4096 f32 (contiguous with S -> one memset)
#define OFF_U    1052672u  // 64x64x256 f32 (e1..e2)
#define OFF_GX   2101248u
#define OFF_WCNT 2105344u
#define OFF_XN   2109440u
#define OFF_CN   2113536u
#define OFF_MD   2117632u
#define OFF_PV   2121728u
#define OFF_PI   2252800u  // ..2383872 slots = 9.54 MB

// ---- out float offsets ----
#define OUT_BMU  1048576u
#define OUT_MD   1056768u

__device__ __forceinline__ void load_lds16(const void* g, void* l) {
  __builtin_amdgcn_global_load_lds(
      (const __attribute__((address_space(1))) unsigned int*)g,
      (__attribute__((address_space(3))) unsigned int*)l, 16, 0, 0);
}

// ---------------- pack f16 hi/lo + norms + Gx (block 0) ----------------
__global__ __launch_bounds__(256) void packnorm_kernel(
    const float* __restrict__ x, const float* __restrict__ cen,
    const float* __restrict__ lr,
    _Float16* __restrict__ Apk, _Float16* __restrict__ Bpk,
    float* __restrict__ xn, float* __restrict__ cn, float* __restrict__ Gx) {
  int row  = blockIdx.x * 4 + (threadIdx.x >> 6);
  int lane = threadIdx.x & 63;
  bool isx = row < BATCH;
  const float* src = isx ? (x + (size_t)row * DIM)
                         : (cen + (size_t)(row - BATCH) * DIM);
  float4 v = *(const float4*)(src + lane * 4);
  _Float16 h0 = (_Float16)v.x, h1 = (_Float16)v.y,
           h2 = (_Float16)v.z, h3 = (_Float16)v.w;
  _Float16 l0 = (_Float16)(v.x - (float)h0), l1 = (_Float16)(v.y - (float)h1),
           l2 = (_Float16)(v.z - (float)h2), l3 = (_Float16)(v.w - (float)h3);
  _Float16* dst = (isx ? Apk : Bpk) + (size_t)(isx ? row : row - BATCH) * 512;
  *(f16x4*)(dst + lane * 4)       = (f16x4){h0, h1, h2, h3};
  *(f16x4*)(dst + 256 + lane * 4) = (f16x4){l0, l1, l2, l3};
  float s = v.x * v.x + v.y * v.y + v.z * v.z + v.w * v.w;
#pragma unroll
  for (int off = 32; off >= 1; off >>= 1) s += __shfl_xor(s, off);
  if (lane == 0) { if (isx) xn[row] = s; else cn[row - BATCH] = s; }
  if (blockIdx.x == 0) {
    float sg  = 32.f * lr[0];
    float inv = 1.f / (2.f * sg * sg + 1e-5f);
#pragma unroll
    for (int i = 0; i < 16; ++i) {
      int g = i * 256 + threadIdx.x;
      float d = (float)((g >> 6) - (g & 63));
      Gx[g] = expf(-d * d * inv);
    }
  }
}

// ---- fused 3-term f16-split GEMM: stage {Ah,Al,Bh,Bl} once per K-chunk,
// ---- 3 MFMAs per fragment pair (hh+hl+lh), BK=32, double-buffered ----
__global__ __launch_bounds__(256) void gemm_argmin_kernel(
    const _Float16* __restrict__ Apk, const _Float16* __restrict__ Bpk,
    const float* __restrict__ cnorm, float* __restrict__ pv, int* __restrict__ pi) {
  __shared__ __align__(16) _Float16 lds[2][4][4096];  // [buf][Ah,Al,Bh,Bl][128r x 32k]
  const int tid  = threadIdx.x;
  const int lane = tid & 63, w = tid >> 6;
  const int wr = w >> 1, wc = w & 1;
  const int row0 = blockIdx.y * 128, col0 = blockIdx.x * 128;
  const int t15 = lane & 15, q = lane >> 4;
  const int rsw = t15 & 3;                        // read-side chunk-swizzle key
  // staging: wave w stages tile w; lane -> (row = i*16 + (lane>>2), chunk)
  const int srow   = lane >> 2;                   // + i*16
  const int schunk = (lane & 3) ^ ((lane >> 2) & 3);  // pre-swizzled source chunk
  const _Float16* sbase = (w < 2) ? (Apk + (size_t)row0 * 512)
                                  : (Bpk + (size_t)col0 * 512);
  const int shalf = (w & 1) ? 256 : 0;            // lo-half for tiles 1,3

  f32x4 acc[4][4];
#pragma unroll
  for (int m = 0; m < 4; ++m)
#pragma unroll
    for (int n = 0; n < 4; ++n) acc[m][n] = (f32x4){0.f, 0.f, 0.f, 0.f};

  auto STAGE = [&](int b, int step) {
    const _Float16* s0 = sbase + shalf + step * 32 + schunk * 8;
    _Float16* dst = &lds[b][w][0];
#pragma unroll
    for (int i = 0; i < 8; ++i)
      load_lds16(s0 + (size_t)(i * 16 + srow) * 512, dst + i * 512);
  };

  STAGE(0, 0);
  for (int t = 0; t < KSTEPS; ++t) {
    const int b = t & 1;
    __syncthreads();                   // tile t staged (barrier drains vmcnt)
    if (t + 1 < KSTEPS) STAGE(b ^ 1, t + 1);
    f16x8 afh[4], afl[4], bfh[4], bfl[4];
#pragma unroll
    for (int m = 0; m < 4; ++m) {
      int r = wr * 64 + m * 16 + t15;
      int c = (q ^ rsw) * 8;
      afh[m] = *(const f16x8*)&lds[b][0][r * 32 + c];
      afl[m] = *(const f16x8*)&lds[b][1][r * 32 + c];
    }
#pragma unroll
    for (int n = 0; n < 4; ++n) {
      int r = wc * 64 + n * 16 + t15;
      int c = (q ^ rsw) * 8;
      bfh[n] = *(const f16x8*)&lds[b][2][r * 32 + c];
      bfl[n] = *(const f16x8*)&lds[b][3][r * 32 + c];
    }
#pragma unroll
    for (int m = 0; m < 4; ++m)
#pragma unroll
      for (int n = 0; n < 4; ++n) {
        acc[m][n] = __builtin_amdgcn_mfma_f32_16x16x32_f16(afh[m], bfh[n], acc[m][n], 0, 0, 0);
        acc[m][n] = __builtin_amdgcn_mfma_f32_16x16x32_f16(afh[m], bfl[n], acc[m][n], 0, 0, 0);
        acc[m][n] = __builtin_amdgcn_mfma_f32_16x16x32_f16(afl[m], bfh[n], acc[m][n], 0, 0, 0);
      }
  }
  __syncthreads();                     // all ds_reads done before LDS reuse

  // epilogue: v = cnorm[c] - 2*dot; per-row first-min over this 128-col block
  float cnv[4];
#pragma unroll
  for (int n = 0; n < 4; ++n) cnv[n] = cnorm[col0 + wc * 64 + n * 16 + t15];

  float* cv = (float*)&lds[0][0][0];   // [128][2]
  int*   ci = (int*)&lds[0][2][0];     // [128][2]
#pragma unroll
  for (int m = 0; m < 4; ++m) {
#pragma unroll
    for (int reg = 0; reg < 4; ++reg) {
      float bv = 1e30f; int bi = 0x7fffffff;
#pragma unroll
      for (int n = 0; n < 4; ++n) {    // cols ascend with n -> first-min
        float v = cnv[n] - 2.f * acc[m][n][reg];
        if (v < bv) { bv = v; bi = col0 + wc * 64 + n * 16 + t15; }
      }
#pragma unroll
      for (int off = 1; off < 16; off <<= 1) {
        float ov = __shfl_xor(bv, off);
        int   oi = __shfl_xor(bi, off);
        if (ov < bv || (ov == bv && oi < bi)) { bv = ov; bi = oi; }
      }
      if (t15 == 0) {
        int r = wr * 64 + m * 16 + q * 4 + reg;
        cv[r * 2 + wc] = bv;
        ci[r * 2 + wc] = bi;
      }
    }
  }
  __syncthreads();
  if (tid < 128) {
    float v0 = cv[tid * 2];     int i0 = ci[tid * 2];
    float v1 = cv[tid * 2 + 1]; int i1 = ci[tid * 2 + 1];
    if (v1 < v0 || (v1 == v0 && i1 < i0)) { v0 = v1; i0 = i1; }
    pv[(size_t)(row0 + tid) * 32 + blockIdx.x] = v0;
    pi[(size_t)(row0 + tid) * 32 + blockIdx.x] = i0;
  }
}

// ------- finalize: 4 rows/block, wavewide reduce, no LDS, scatter S/cnt -------
__global__ __launch_bounds__(256) void finalize_kernel(
    const float* __restrict__ pv, const int* __restrict__ pi,
    const float* __restrict__ xn, const float* __restrict__ x,
    float* __restrict__ S, float* __restrict__ cnt,
    float* __restrict__ md, float* __restrict__ out) {
  const int w = threadIdx.x >> 6, l = threadIdx.x & 63;
  const int b = blockIdx.x * 4 + w;
  float v = pv[(size_t)b * 32 + (l & 31)];     // both 32-halves load same data
  int idx  = pi[(size_t)b * 32 + (l & 31)];
#pragma unroll
  for (int off = 16; off >= 1; off >>= 1) {
    float ov = __shfl_xor(v, off);
    int   oi = __shfl_xor(idx, off);
    if (ov < v || (ov == v && oi < idx)) { v = ov; idx = oi; }
  }
  if (l == 0) {
    md[b] = sqrtf(fmaxf(xn[b] + v, 0.f));
    out[OUT_BMU + (size_t)b * 2 + 0] = (float)(idx >> 6);
    out[OUT_BMU + (size_t)b * 2 + 1] = (float)(idx & 63);
    atomicAdd(cnt + idx, 1.f);
  }
#pragma unroll
  for (int c = 0; c < 4; ++c)
    atomicAdd(S + (size_t)idx * DIM + c * 64 + l, x[(size_t)b * DIM + c * 64 + l]);
}

// --- e1 (blk 0-255) || wcnt (blk 256-271) || md-reduce (blk 272) ---
__global__ __launch_bounds__(256) void e1_kernel(const float* __restrict__ S,
                                                 const float* __restrict__ Gx,
                                                 const float* __restrict__ cnt,
                                                 const float* __restrict__ md,
                                                 float* __restrict__ U,
                                                 float* __restrict__ Wcnt,
                                                 float* __restrict__ out) {
  __shared__ float smem[12288];        // 48 KiB shared across branches
  const int bid = blockIdx.x, tid = threadIdx.x;
  if (bid < 256) {
    float* Ss = smem;                  // [64 ki][64 dd]
    const int dd = tid & 63, gq = tid >> 6;
    const int kj = bid >> 2, dq = bid & 3;
#pragma unroll 4
    for (int i = 0; i < 16; ++i) {
      int ki = i * 4 + gq;
      Ss[ki * 64 + dd] = S[((size_t)ki * 64 + kj) * 256 + dq * 64 + dd];
    }
    __syncthreads();
    float a[16];
#pragma unroll
    for (int gg = 0; gg < 16; ++gg) a[gg] = 0.f;
    for (int ki = 0; ki < 64; ++ki) {
      float s = Ss[ki * 64 + dd];
#pragma unroll
      for (int gg = 0; gg < 16; ++gg)
        a[gg] += Gx[ki * 64 + gq * 16 + gg] * s;   // wave-uniform -> s_load
    }
#pragma unroll
    for (int gg = 0; gg < 16; ++gg)
      U[((size_t)(gq * 16 + gg) * 64 + kj) * 256 + dq * 64 + dd] = a[gg];
  } else if (bid < 272) {
    float* cs = smem;
    float* gs = smem + 4096;
    float* inner = smem + 8192;
    for (int i = 0; i < 16; i++) { cs[i * 256 + tid] = cnt[i * 256 + tid]; gs[i * 256 + tid] = Gx[i * 256 + tid]; }
    __syncthreads();
    for (int i = 0; i < 16; i++) {
      int idx = i * 256 + tid; int ki = idx >> 6, gj = idx & 63;
      float a = 0.f;
      for (int kj = 0; kj < 64; kj++) a += gs[kj * 64 + gj] * cs[ki * 64 + kj];
      inner[idx] = a;
    }
    __syncthreads();
    const int g = (bid - 256) * 256 + tid, gi = g >> 6, gj = g & 63;
    float a = 0.f;
    for (int ki = 0; ki < 64; ki++) a += gs[gi * 64 + ki] * inner[ki * 64 + gj];
    Wcnt[g] = a;
  } else {
    float s = 0.f;
#pragma unroll
    for (int i = 0; i < 16; i++) s += md[i * 256 + tid];
#pragma unroll
    for (int off = 32; off >= 1; off >>= 1) s += __shfl_xor(s, off);
    if ((tid & 63) == 0) smem[tid >> 6] = s;
    __syncthreads();
    if (tid == 0) out[OUT_MD] = (smem[0] + smem[1] + smem[2] + smem[3]) * (1.f / (float)BATCH);
  }
}

// --- e2 + fused centroid write ; grid (gi,dquad)=256 ---
__global__ __launch_bounds__(256) void e2_kernel(const float* __restrict__ U,
                                                 const float* __restrict__ Gx,
                                                 const float* __restrict__ Wcnt,
                                                 const float* __restrict__ cen,
                                                 const float* __restrict__ lr,
                                                 float* __restrict__ out) {
  __shared__ float Us[4096];           // [64 kj][64 dd]
  const int t = threadIdx.x, dd = t & 63, gq = t >> 6;
  const int gi = blockIdx.x >> 2, dq = blockIdx.x & 3;
#pragma unroll 4
  for (int i = 0; i < 16; ++i) {
    int kj = i * 4 + gq;
    Us[kj * 64 + dd] = U[((size_t)gi * 64 + kj) * 256 + dq * 64 + dd];
  }
  __syncthreads();
  float a[16];
#pragma unroll
  for (int gg = 0; gg < 16; ++gg) a[gg] = 0.f;
  for (int kj = 0; kj < 64; ++kj) {
    float s = Us[kj * 64 + dd];
#pragma unroll
    for (int gg = 0; gg < 16; ++gg)
      a[gg] += Gx[kj * 64 + gq * 16 + gg] * s;
  }
  const float coef = 0.5f * lr[0] / (float)BATCH;
#pragma unroll
  for (int gg = 0; gg < 16; ++gg) {
    int g = gi * 64 + gq * 16 + gg;
    float c = cen[(size_t)g * 256 + dq * 64 + dd];
    out[(size_t)g * 256 + dq * 64 + dd] = c + coef * (a[gg] - Wcnt[g] * c);
  }
}

extern "C" void kernel_launch(void* const* d_in, const int* in_sizes, int n_in,
                              void* d_out, int out_size, void* d_ws, size_t ws_size,
                              hipStream_t stream) {
  const float* x   = (const float*)d_in[0];
  const float* cen = (const float*)d_in[1];
  const float* lr  = (const float*)d_in[4];
  float* out = (float*)d_out;
  float* ws  = (float*)d_ws;

  _Float16* Apk = (_Float16*)(ws + OFF_APK);
  _Float16* Bpk = (_Float16*)(ws + OFF_BPK);
  float* S    = ws + OFF_S;
  float* cnt  = ws + OFF_CNT;
  float* U    = ws + OFF_U;
  float* Gx   = ws + OFF_GX;
  float* Wcnt = ws + OFF_WCNT;
  float* xn   = ws + OFF_XN;
  float* cnw  = ws + OFF_CN;
  float* md   = ws + OFF_MD;
  float* pv   = ws + OFF_PV;
  int*   pi   = (int*)(ws + OFF_PI);

  packnorm_kernel<<<2048, 256, 0, stream>>>(x, cen, lr, Apk, Bpk, xn, cnw, Gx);
  gemm_argmin_kernel<<<dim3(32, 32), 256, 0, stream>>>(Apk, Bpk, cnw, pv, pi);
  hipMemsetAsync(S, 0, (size_t)(1048576 + 4096) * sizeof(float), stream);  // S+cnt
  finalize_kernel<<<1024, 256, 0, stream>>>(pv, pi, xn, x, S, cnt, md, out);
  e1_kernel<<<273, 256, 0, stream>>>(S, Gx, cnt, md, U, Wcnt, out);
  e2_kernel<<<256, 256, 0, stream>>>(U, Gx, Wcnt, cen, lr, out);
}

// Round 10
// 178.334 us; speedup vs baseline: 2.7009x; 1.0135x over previous
//
#include <hip/hip_runtime.h>
#include <cstdint>
#include <cstddef>

#define DIM    256
#define BATCH  4096
#define KSTEPS 8            // K=256, BK=32

typedef _Float16 f16x8 __attribute__((ext_vector_type(8)));
typedef _Float16 f16x4 __attribute__((ext_vector_type(4)));
typedef float    f32x4 __attribute__((ext_vector_type(4)));

// ---- ws float-slot offsets (regions overlap across pipeline phases) ----
#define OFF_APK  0u        // 4096x512 halfs [hi|lo] (pack..gemm)
#define OFF_S    0u        // 4096x256 f32 (memset after gemm)
#define OFF_BPK  1048576u  // 4096x512 halfs (pack..gemm)
#define OFF_CNT  1048576u  // 4096 f32 (contiguous with S -> one memset)
#define OFF_U    1052672u  // 64x64x256 f32 (e1..e2)
#define OFF_GX   2101248u
#define OFF_WCNT 2105344u
#define OFF_XN   2109440u
#define OFF_CN   2113536u
#define OFF_MD   2117632u
#define OFF_PV   2121728u
#define OFF_PI   2252800u  // ..2383872 slots = 9.54 MB

// ---- out float offsets ----
#define OUT_BMU  1048576u
#define OUT_MD   1056768u

__device__ __forceinline__ void load_lds16(const void* g, void* l) {
  __builtin_amdgcn_global_load_lds(
      (const __attribute__((address_space(1))) unsigned int*)g,
      (__attribute__((address_space(3))) unsigned int*)l, 16, 0, 0);
}

// ---------------- pack f16 hi/lo + norms + Gx (block 0) ----------------
__global__ __launch_bounds__(256) void packnorm_kernel(
    const float* __restrict__ x, const float* __restrict__ cen,
    const float* __restrict__ lr,
    _Float16* __restrict__ Apk, _Float16* __restrict__ Bpk,
    float* __restrict__ xn, float* __restrict__ cn, float* __restrict__ Gx) {
  int row  = blockIdx.x * 4 + (threadIdx.x >> 6);
  int lane = threadIdx.x & 63;
  bool isx = row < BATCH;
  const float* src = isx ? (x + (size_t)row * DIM)
                         : (cen + (size_t)(row - BATCH) * DIM);
  float4 v = *(const float4*)(src + lane * 4);
  _Float16 h0 = (_Float16)v.x, h1 = (_Float16)v.y,
           h2 = (_Float16)v.z, h3 = (_Float16)v.w;
  _Float16 l0 = (_Float16)(v.x - (float)h0), l1 = (_Float16)(v.y - (float)h1),
           l2 = (_Float16)(v.z - (float)h2), l3 = (_Float16)(v.w - (float)h3);
  _Float16* dst = (isx ? Apk : Bpk) + (size_t)(isx ? row : row - BATCH) * 512;
  *(f16x4*)(dst + lane * 4)       = (f16x4){h0, h1, h2, h3};
  *(f16x4*)(dst + 256 + lane * 4) = (f16x4){l0, l1, l2, l3};
  float s = v.x * v.x + v.y * v.y + v.z * v.z + v.w * v.w;
#pragma unroll
  for (int off = 32; off >= 1; off >>= 1) s += __shfl_xor(s, off);
  if (lane == 0) { if (isx) xn[row] = s; else cn[row - BATCH] = s; }
  if (blockIdx.x == 0) {
    float sg  = 32.f * lr[0];
    float inv = 1.f / (2.f * sg * sg + 1e-5f);
#pragma unroll
    for (int i = 0; i < 16; ++i) {
      int g = i * 256 + threadIdx.x;
      float d = (float)((g >> 6) - (g & 63));
      Gx[g] = expf(-d * d * inv);
    }
  }
}

// ---- fused 3-term f16-split GEMM, BK=32, double-buffered.
// ---- LDS tile stored row-PAIRED: [64 phys rows x 64 halfs], slot swizzle
// ---- slot = ((r&1)*4 + c2) ^ (row'&7)  -> conflict-free b128 reads ----
__global__ __launch_bounds__(256) void gemm_argmin_kernel(
    const _Float16* __restrict__ Apk, const _Float16* __restrict__ Bpk,
    const float* __restrict__ cnorm, float* __restrict__ pv, int* __restrict__ pi) {
  __shared__ __align__(16) _Float16 lds[2][4][4096];  // [buf][Ah,Al,Bh,Bl][64x64]
  const int tid  = threadIdx.x;
  const int lane = tid & 63, w = tid >> 6;
  const int wr = w >> 1, wc = w & 1;
  const int row0 = blockIdx.y * 128, col0 = blockIdx.x * 128;
  const int t15 = lane & 15, q = lane >> 4;
  // read-side phys coords
  const int rp      = t15 >> 1;                 // row-pair index 0..7
  const int slotkey = (t15 & 1) * 4;            // + q, then ^ rp
  // staging: wave w stages tile w; invert swizzle on global source
  const int sv   = (lane & 7) ^ ((lane >> 3) & 7);
  const int srb  = (lane >> 3) * 2 + (sv >> 2); // row within 16-row group
  const int sc2  = sv & 3;                      // chunk
  const _Float16* sbase = (w < 2) ? (Apk + (size_t)row0 * 512)
                                  : (Bpk + (size_t)col0 * 512);
  const int shalf = (w & 1) ? 256 : 0;          // lo-half for tiles 1,3

  f32x4 acc[4][4];
#pragma unroll
  for (int m = 0; m < 4; ++m)
#pragma unroll
    for (int n = 0; n < 4; ++n) acc[m][n] = (f32x4){0.f, 0.f, 0.f, 0.f};

  auto STAGE = [&](int b, int step) {
    const _Float16* s0 = sbase + shalf + step * 32 + (size_t)srb * 512 + sc2 * 8;
    _Float16* dst = &lds[b][w][0];
#pragma unroll
    for (int i = 0; i < 8; ++i)
      load_lds16(s0 + (size_t)i * 16 * 512, dst + i * 512);
  };

  STAGE(0, 0);
  for (int t = 0; t < KSTEPS; ++t) {
    const int b = t & 1;
    __syncthreads();                   // tile t staged (barrier drains vmcnt)
    if (t + 1 < KSTEPS) STAGE(b ^ 1, t + 1);
    f16x8 afh[4], afl[4], bfh[4], bfl[4];
#pragma unroll
    for (int m = 0; m < 4; ++m) {
      int off = (wr * 32 + m * 8 + rp) * 64 + (((slotkey + q) ^ rp) * 8);
      afh[m] = *(const f16x8*)&lds[b][0][off];
      afl[m] = *(const f16x8*)&lds[b][1][off];
    }
#pragma unroll
    for (int n = 0; n < 4; ++n) {
      int off = (wc * 32 + n * 8 + rp) * 64 + (((slotkey + q) ^ rp) * 8);
      bfh[n] = *(const f16x8*)&lds[b][2][off];
      bfl[n] = *(const f16x8*)&lds[b][3][off];
    }
#pragma unroll
    for (int m = 0; m < 4; ++m)
#pragma unroll
      for (int n = 0; n < 4; ++n) {
        acc[m][n] = __builtin_amdgcn_mfma_f32_16x16x32_f16(afh[m], bfh[n], acc[m][n], 0, 0, 0);
        acc[m][n] = __builtin_amdgcn_mfma_f32_16x16x32_f16(afh[m], bfl[n], acc[m][n], 0, 0, 0);
        acc[m][n] = __builtin_amdgcn_mfma_f32_16x16x32_f16(afl[m], bfh[n], acc[m][n], 0, 0, 0);
      }
  }
  __syncthreads();                     // all ds_reads done before LDS reuse

  // epilogue: v = cnorm[c] - 2*dot; per-row first-min over this 128-col block
  float cnv[4];
#pragma unroll
  for (int n = 0; n < 4; ++n) cnv[n] = cnorm[col0 + wc * 64 + n * 16 + t15];

  float* cv = (float*)&lds[0][0][0];   // [128][2]
  int*   ci = (int*)&lds[0][2][0];     // [128][2]
#pragma unroll
  for (int m = 0; m < 4; ++m) {
#pragma unroll
    for (int reg = 0; reg < 4; ++reg) {
      float bv = 1e30f; int bi = 0x7fffffff;
#pragma unroll
      for (int n = 0; n < 4; ++n) {    // cols ascend with n -> first-min
        float v = cnv[n] - 2.f * acc[m][n][reg];
        if (v < bv) { bv = v; bi = col0 + wc * 64 + n * 16 + t15; }
      }
#pragma unroll
      for (int off = 1; off < 16; off <<= 1) {
        float ov = __shfl_xor(bv, off);
        int   oi = __shfl_xor(bi, off);
        if (ov < bv || (ov == bv && oi < bi)) { bv = ov; bi = oi; }
      }
      if (t15 == 0) {
        int r = wr * 64 + m * 16 + q * 4 + reg;
        cv[r * 2 + wc] = bv;
        ci[r * 2 + wc] = bi;
      }
    }
  }
  __syncthreads();
  if (tid < 128) {
    float v0 = cv[tid * 2];     int i0 = ci[tid * 2];
    float v1 = cv[tid * 2 + 1]; int i1 = ci[tid * 2 + 1];
    if (v1 < v0 || (v1 == v0 && i1 < i0)) { v0 = v1; i0 = i1; }
    pv[(size_t)(row0 + tid) * 32 + blockIdx.x] = v0;
    pi[(size_t)(row0 + tid) * 32 + blockIdx.x] = i0;
  }
}

// ------- finalize: 4 rows/block, wavewide reduce, no LDS, scatter S/cnt -------
__global__ __launch_bounds__(256) void finalize_kernel(
    const float* __restrict__ pv, const int* __restrict__ pi,
    const float* __restrict__ xn, const float* __restrict__ x,
    float* __restrict__ S, float* __restrict__ cnt,
    float* __restrict__ md, float* __restrict__ out) {
  const int w = threadIdx.x >> 6, l = threadIdx.x & 63;
  const int b = blockIdx.x * 4 + w;
  float v = pv[(size_t)b * 32 + (l & 31)];     // both 32-halves load same data
  int idx  = pi[(size_t)b * 32 + (l & 31)];
#pragma unroll
  for (int off = 16; off >= 1; off >>= 1) {
    float ov = __shfl_xor(v, off);
    int   oi = __shfl_xor(idx, off);
    if (ov < v || (ov == v && oi < idx)) { v = ov; idx = oi; }
  }
  if (l == 0) {
    md[b] = sqrtf(fmaxf(xn[b] + v, 0.f));
    out[OUT_BMU + (size_t)b * 2 + 0] = (float)(idx >> 6);
    out[OUT_BMU + (size_t)b * 2 + 1] = (float)(idx & 63);
    atomicAdd(cnt + idx, 1.f);
  }
#pragma unroll
  for (int c = 0; c < 4; ++c)
    atomicAdd(S + (size_t)idx * DIM + c * 64 + l, x[(size_t)b * DIM + c * 64 + l]);
}

// --- e1 (blk 0-255) || wcnt (blk 256-271) || md-reduce (blk 272) ---
__global__ __launch_bounds__(256) void e1_kernel(const float* __restrict__ S,
                                                 const float* __restrict__ Gx,
                                                 const float* __restrict__ cnt,
                                                 const float* __restrict__ md,
                                                 float* __restrict__ U,
                                                 float* __restrict__ Wcnt,
                                                 float* __restrict__ out) {
  __shared__ float smem[12288];        // 48 KiB shared across branches
  const int bid = blockIdx.x, tid = threadIdx.x;
  if (bid < 256) {
    float* Ss = smem;                  // [64 ki][64 dd]
    const int dd = tid & 63, gq = tid >> 6;
    const int kj = bid >> 2, dq = bid & 3;
#pragma unroll 4
    for (int i = 0; i < 16; ++i) {
      int ki = i * 4 + gq;
      Ss[ki * 64 + dd] = S[((size_t)ki * 64 + kj) * 256 + dq * 64 + dd];
    }
    __syncthreads();
    float a[16];
#pragma unroll
    for (int gg = 0; gg < 16; ++gg) a[gg] = 0.f;
    for (int ki = 0; ki < 64; ++ki) {
      float s = Ss[ki * 64 + dd];
#pragma unroll
      for (int gg = 0; gg < 16; ++gg)
        a[gg] += Gx[ki * 64 + gq * 16 + gg] * s;   // wave-uniform -> s_load
    }
#pragma unroll
    for (int gg = 0; gg < 16; ++gg)
      U[((size_t)(gq * 16 + gg) * 64 + kj) * 256 + dq * 64 + dd] = a[gg];
  } else if (bid < 272) {
    float* cs = smem;
    float* gs = smem + 4096;
    float* inner = smem + 8192;
    for (int i = 0; i < 16; i++) { cs[i * 256 + tid] = cnt[i * 256 + tid]; gs[i * 256 + tid] = Gx[i * 256 + tid]; }
    __syncthreads();
    for (int i = 0; i < 16; i++) {
      int idx = i * 256 + tid; int ki = idx >> 6, gj = idx & 63;
      float a = 0.f;
      for (int kj = 0; kj < 64; kj++) a += gs[kj * 64 + gj] * cs[ki * 64 + kj];
      inner[idx] = a;
    }
    __syncthreads();
    const int g = (bid - 256) * 256 + tid, gi = g >> 6, gj = g & 63;
    float a = 0.f;
    for (int ki = 0; ki < 64; ki++) a += gs[gi * 64 + ki] * inner[ki * 64 + gj];
    Wcnt[g] = a;
  } else {
    float s = 0.f;
#pragma unroll
    for (int i = 0; i < 16; i++) s += md[i * 256 + tid];
#pragma unroll
    for (int off = 32; off >= 1; off >>= 1) s += __shfl_xor(s, off);
    if ((tid & 63) == 0) smem[tid >> 6] = s;
    __syncthreads();
    if (tid == 0) out[OUT_MD] = (smem[0] + smem[1] + smem[2] + smem[3]) * (1.f / (float)BATCH);
  }
}

// --- e2 + fused centroid write ; grid (gi,dquad)=256 ---
__global__ __launch_bounds__(256) void e2_kernel(const float* __restrict__ U,
                                                 const float* __restrict__ Gx,
                                                 const float* __restrict__ Wcnt,
                                                 const float* __restrict__ cen,
                                                 const float* __restrict__ lr,
                                                 float* __restrict__ out) {
  __shared__ float Us[4096];           // [64 kj][64 dd]
  const int t = threadIdx.x, dd = t & 63, gq = t >> 6;
  const int gi = blockIdx.x >> 2, dq = blockIdx.x & 3;
#pragma unroll 4
  for (int i = 0; i < 16; ++i) {
    int kj = i * 4 + gq;
    Us[kj * 64 + dd] = U[((size_t)gi * 64 + kj) * 256 + dq * 64 + dd];
  }
  __syncthreads();
  float a[16];
#pragma unroll
  for (int gg = 0; gg < 16; ++gg) a[gg] = 0.f;
  for (int kj = 0; kj < 64; ++kj) {
    float s = Us[kj * 64 + dd];
#pragma unroll
    for (int gg = 0; gg < 16; ++gg)
      a[gg] += Gx[kj * 64 + gq * 16 + gg] * s;
  }
  const float coef = 0.5f * lr[0] / (float)BATCH;
#pragma unroll
  for (int gg = 0; gg < 16; ++gg) {
    int g = gi * 64 + gq * 16 + gg;
    float c = cen[(size_t)g * 256 + dq * 64 + dd];
    out[(size_t)g * 256 + dq * 64 + dd] = c + coef * (a[gg] - Wcnt[g] * c);
  }
}

extern "C" void kernel_launch(void* const* d_in, const int* in_sizes, int n_in,
                              void* d_out, int out_size, void* d_ws, size_t ws_size,
                              hipStream_t stream) {
  const float* x   = (const float*)d_in[0];
  const float* cen = (const float*)d_in[1];
  const float* lr  = (const float*)d_in[4];
  float* out = (float*)d_out;
  float* ws  = (float*)d_ws;

  _Float16* Apk = (_Float16*)(ws + OFF_APK);
  _Float16* Bpk = (_Float16*)(ws + OFF_BPK);
  float* S    = ws + OFF_S;
  float* cnt  = ws + OFF_CNT;
  float* U    = ws + OFF_U;
  float* Gx   = ws + OFF_GX;
  float* Wcnt = ws + OFF_WCNT;
  float* xn   = ws + OFF_XN;
  float* cnw  = ws + OFF_CN;
  float* md   = ws + OFF_MD;
  float* pv   = ws + OFF_PV;
  int*   pi   = (int*)(ws + OFF_PI);

  packnorm_kernel<<<2048, 256, 0, stream>>>(x, cen, lr, Apk, Bpk, xn, cnw, Gx);
  gemm_argmin_kernel<<<dim3(32, 32), 256, 0, stream>>>(Apk, Bpk, cnw, pv, pi);
  hipMemsetAsync(S, 0, (size_t)(1048576 + 4096) * sizeof(float), stream);  // S+cnt
  finalize_kernel<<<1024, 256, 0, stream>>>(pv, pi, xn, x, S, cnt, md, out);
  e1_kernel<<<273, 256, 0, stream>>>(S, Gx, cnt, md, U, Wcnt, out);
  e2_kernel<<<256, 256, 0, stream>>>(U, Gx, Wcnt, cen, lr, out);
}